// Round 1
// baseline (942.359 us; speedup 1.0000x reference)
//
#include <hip/hip_runtime.h>
#include <hip/hip_bf16.h>
#include <stdint.h>

// MoE top-2 (T=8192, D=1024, H=2816, E=8) — sparse grouped-GEMM implementation.
// Pipeline: router -> offsets/aux -> gather(bf16) -> GEMM1(w1,w3 fused SiLU*) ->
//           GEMM2(w2) -> weighted combine. Weights transposed+converted to bf16
//           each launch (stateless). All GEMMs: 128x128 tile, BK=32, 4 waves,
//           mfma_f32_16x16x32_bf16, global_load_lds(16B) with XOR granule swizzle.

#define T_TOK 8192
#define D_DIM 1024
#define H_DIM 2816
#define E_EXP 8
#define NSLOT 16384       // T * 2
#define CAP_ROWS 17408    // 16384 + 8*128 padding capacity
#define MT_MAX 136

// meta int layout
#define MI_TOTAL 0
#define MI_CNT 8
#define MI_POS 16
#define MI_MTE 32
#define MI_MTB (32 + MT_MAX)

typedef __attribute__((ext_vector_type(8))) short short8;
typedef __attribute__((ext_vector_type(4))) float f32x4;

#define GLD16(gsrc, ldst) __builtin_amdgcn_global_load_lds( \
    (const __attribute__((address_space(1))) void*)(gsrc),  \
    (__attribute__((address_space(3))) void*)(ldst), 16, 0, 0)

// ---------------- init ----------------
__global__ __launch_bounds__(64) void init_kernel(int* meta) {
  if (threadIdx.x < E_EXP) meta[MI_CNT + threadIdx.x] = 0;
}

// ---------------- weight transpose + f32->bf16 ----------------
// in: (E, R, C) f32   out: (E, C, R) bf16
template <int R, int C>
__global__ __launch_bounds__(256) void transpose_convert(const float* __restrict__ in,
                                                         __hip_bfloat16* __restrict__ outp) {
  int e = blockIdx.z;
  int c0 = blockIdx.x * 32, r0 = blockIdx.y * 32;
  __shared__ float tile[32][33];
  int tc = threadIdx.x & 31, tr = threadIdx.x >> 5;  // 32 cols x 8 rows
  const float* src = in + ((size_t)e * R + r0) * C + c0;
#pragma unroll
  for (int i = 0; i < 4; i++) tile[tr + i * 8][tc] = src[(size_t)(tr + i * 8) * C + tc];
  __syncthreads();
  __hip_bfloat16* dst = outp + ((size_t)e * C + c0) * R + r0;
#pragma unroll
  for (int i = 0; i < 4; i++)
    dst[(size_t)(tr + i * 8) * R + tc] = __float2bfloat16(tile[tc][tr + i * 8]);
}

// ---------------- router ----------------
__global__ __launch_bounds__(256) void router_kernel(const float* __restrict__ x,
                                                     const float* __restrict__ Wr,
                                                     int* __restrict__ meta,
                                                     float* __restrict__ Pbuf,
                                                     int* __restrict__ expert_sel,
                                                     float* __restrict__ slot_w) {
  int wave = threadIdx.x >> 6, lane = threadIdx.x & 63;
  int tok = blockIdx.x * 4 + wave;
  const float* xr = x + (size_t)tok * D_DIM;
  float acc[8];
#pragma unroll
  for (int e = 0; e < 8; e++) acc[e] = 0.f;
  for (int d = lane; d < D_DIM; d += 64) {
    float xv = xr[d];
    const float4* w4 = (const float4*)(Wr + d * 8);
    float4 wa = w4[0], wb = w4[1];
    acc[0] += xv * wa.x; acc[1] += xv * wa.y; acc[2] += xv * wa.z; acc[3] += xv * wa.w;
    acc[4] += xv * wb.x; acc[5] += xv * wb.y; acc[6] += xv * wb.z; acc[7] += xv * wb.w;
  }
#pragma unroll
  for (int e = 0; e < 8; e++) {
#pragma unroll
    for (int off = 32; off >= 1; off >>= 1) acc[e] += __shfl_xor(acc[e], off);
  }
  // softmax over 8 (all lanes redundantly)
  float mx = acc[0];
#pragma unroll
  for (int e = 1; e < 8; e++) mx = fmaxf(mx, acc[e]);
  float p[8], s = 0.f;
#pragma unroll
  for (int e = 0; e < 8; e++) { p[e] = expf(acc[e] - mx); s += p[e]; }
  float inv = 1.f / s;
#pragma unroll
  for (int e = 0; e < 8; e++) p[e] *= inv;
  // top-2, lowest index wins ties (matches lax.top_k)
  int i0 = 0;
#pragma unroll
  for (int e = 1; e < 8; e++) if (p[e] > p[i0]) i0 = e;
  int i1 = (i0 == 0) ? 1 : 0;
#pragma unroll
  for (int e = 0; e < 8; e++) if (e != i0 && p[e] > p[i1]) i1 = e;
  float wsum = p[i0] + p[i1];

  __shared__ float sP[4][8];
  if (lane == 0) {
    expert_sel[tok * 2] = i0;
    expert_sel[tok * 2 + 1] = i1;
    slot_w[tok * 2] = p[i0] / wsum;
    slot_w[tok * 2 + 1] = p[i1] / wsum;
    atomicAdd(&meta[MI_CNT + i0], 1);
    atomicAdd(&meta[MI_CNT + i1], 1);
#pragma unroll
    for (int e = 0; e < 8; e++) sP[wave][e] = p[e];
  }
  __syncthreads();
  if (threadIdx.x < 8)
    Pbuf[blockIdx.x * 8 + threadIdx.x] =
        sP[0][threadIdx.x] + sP[1][threadIdx.x] + sP[2][threadIdx.x] + sP[3][threadIdx.x];
}

// ---------------- offsets + aux loss ----------------
__global__ __launch_bounds__(64) void offsets_kernel(int* __restrict__ meta,
                                                     const float* __restrict__ Pbuf,
                                                     float* __restrict__ aux_out) {
  int t = threadIdx.x;
  __shared__ float psum[8];
  if (t < 8) {
    float s = 0.f;
    for (int b = 0; b < 2048; b++) s += Pbuf[b * 8 + t];  // fixed order: deterministic
    psum[t] = s;
  }
  __syncthreads();
  if (t == 0) {
    int off = 0, nt = 0;
    float aux = 0.f;
    for (int e = 0; e < 8; e++) {
      int c = meta[MI_CNT + e];
      meta[MI_POS + e] = off;
      int tiles = (c + 127) >> 7;
      for (int j = 0; j < tiles; j++) { meta[MI_MTE + nt] = e; meta[MI_MTB + nt] = off + j * 128; nt++; }
      off += tiles * 128;
      aux += ((float)c / 16384.f) * (psum[e] / 8192.f);
    }
    meta[MI_TOTAL] = nt;
    *aux_out = 8.f * aux;
  }
}

// ---------------- assign position + gather x row as bf16 ----------------
__global__ __launch_bounds__(256) void assign_gather_kernel(const int* __restrict__ expert_sel,
                                                            int* __restrict__ meta,
                                                            int* __restrict__ slot_pos,
                                                            const float* __restrict__ x,
                                                            __hip_bfloat16* __restrict__ Xg) {
  int slot = blockIdx.x;
  __shared__ int spos;
  if (threadIdx.x == 0) {
    int e = expert_sel[slot];
    int pz = atomicAdd(&meta[MI_POS + e], 1);
    slot_pos[slot] = pz;
    spos = pz;
  }
  __syncthreads();
  int pos = spos;
  int tok = slot >> 1;
  float4 v = ((const float4*)(x + (size_t)tok * D_DIM))[threadIdx.x];
  union { ushort4 u4; __hip_bfloat16 h[4]; } cv;
  cv.h[0] = __float2bfloat16(v.x);
  cv.h[1] = __float2bfloat16(v.y);
  cv.h[2] = __float2bfloat16(v.z);
  cv.h[3] = __float2bfloat16(v.w);
  *(ushort4*)(Xg + (size_t)pos * D_DIM + threadIdx.x * 4) = cv.u4;
}

// ---------------- GEMM helpers ----------------
// LDS tile: [128 rows][32 bf16] = 8192B, 16B granule g XOR-swizzled with (row>>1)&3.
__device__ __forceinline__ short8 frag_read(const char* tile, int row, int kg) {
  int byte = (row << 6) | ((kg ^ ((row >> 1) & 3)) << 4);
  return *(const short8*)(tile + byte);
}

__device__ __forceinline__ void stage_tile16(const __hip_bfloat16* gbase, int ld, char* tile,
                                             int wave, int lane) {
#pragma unroll
  for (int i = 0; i < 2; i++) {
    int L = i * 4096 + wave * 1024 + lane * 16;
    int row = L >> 6;
    int g = (L >> 4) & 3;
    int gs = g ^ ((row >> 1) & 3);  // pre-swizzled global source, linear LDS dest
    const char* src = (const char*)(gbase + (size_t)row * ld) + gs * 16;
    GLD16(src, tile + i * 4096 + wave * 1024);
  }
}

// ---------------- GEMM1: H = silu(Xg @ w1t^T) * (Xg @ w3t^T), bf16 out ----------------
__global__ __launch_bounds__(256, 2) void gemm1_kernel(const __hip_bfloat16* __restrict__ Xg,
                                                       const __hip_bfloat16* __restrict__ w1t,
                                                       const __hip_bfloat16* __restrict__ w3t,
                                                       __hip_bfloat16* __restrict__ Hb,
                                                       const int* __restrict__ meta) {
  int m = blockIdx.y;
  if (m >= meta[MI_TOTAL]) return;
  int e = meta[MI_MTE + m];
  int row0 = meta[MI_MTB + m];
  int n0 = blockIdx.x * 128;
  __shared__ __align__(16) char ldsA[8192];
  __shared__ __align__(16) char ldsB1[8192];
  __shared__ __align__(16) char ldsB3[8192];
  int wave = threadIdx.x >> 6, lane = threadIdx.x & 63;
  int wr = wave >> 1, wc = wave & 1;
  const __hip_bfloat16* Ab = Xg + (size_t)row0 * D_DIM;
  const __hip_bfloat16* B1b = w1t + ((size_t)e * H_DIM + n0) * D_DIM;
  const __hip_bfloat16* B3b = w3t + ((size_t)e * H_DIM + n0) * D_DIM;

  f32x4 acc1[4][4], acc3[4][4];
#pragma unroll
  for (int i = 0; i < 4; i++)
#pragma unroll
    for (int j = 0; j < 4; j++) { acc1[i][j] = 0.f; acc3[i][j] = 0.f; }

  int rsel = lane & 15, kg = lane >> 4;
  for (int k0 = 0; k0 < D_DIM; k0 += 32) {
    stage_tile16(Ab + k0, D_DIM, ldsA, wave, lane);
    stage_tile16(B1b + k0, D_DIM, ldsB1, wave, lane);
    stage_tile16(B3b + k0, D_DIM, ldsB3, wave, lane);
    asm volatile("s_waitcnt vmcnt(0)" ::: "memory");
    __syncthreads();
    short8 a[4], b1[4], b3[4];
#pragma unroll
    for (int f = 0; f < 4; f++) a[f] = frag_read(ldsA, wr * 64 + f * 16 + rsel, kg);
#pragma unroll
    for (int f = 0; f < 4; f++) b1[f] = frag_read(ldsB1, wc * 64 + f * 16 + rsel, kg);
#pragma unroll
    for (int f = 0; f < 4; f++) b3[f] = frag_read(ldsB3, wc * 64 + f * 16 + rsel, kg);
#pragma unroll
    for (int fm = 0; fm < 4; fm++)
#pragma unroll
      for (int fn = 0; fn < 4; fn++) {
        acc1[fm][fn] = __builtin_amdgcn_mfma_f32_16x16x32_bf16(a[fm], b1[fn], acc1[fm][fn], 0, 0, 0);
        acc3[fm][fn] = __builtin_amdgcn_mfma_f32_16x16x32_bf16(a[fm], b3[fn], acc3[fm][fn], 0, 0, 0);
      }
    __syncthreads();
  }
  int rq = lane >> 4;
#pragma unroll
  for (int fm = 0; fm < 4; fm++)
#pragma unroll
    for (int fn = 0; fn < 4; fn++)
#pragma unroll
      for (int j = 0; j < 4; j++) {
        int r = wr * 64 + fm * 16 + rq * 4 + j;
        int c = wc * 64 + fn * 16 + rsel;
        float v1 = acc1[fm][fn][j], v3 = acc3[fm][fn][j];
        float h = (v1 / (1.f + expf(-v1))) * v3;  // silu(v1)*v3
        Hb[(size_t)(row0 + r) * H_DIM + (n0 + c)] = __float2bfloat16(h);
      }
}

// ---------------- GEMM2: Y = Hb @ w2t^T (fp32 out) ----------------
__global__ __launch_bounds__(256, 2) void gemm2_kernel(const __hip_bfloat16* __restrict__ Hb,
                                                       const __hip_bfloat16* __restrict__ w2t,
                                                       float* __restrict__ Y,
                                                       const int* __restrict__ meta) {
  int m = blockIdx.y;
  if (m >= meta[MI_TOTAL]) return;
  int e = meta[MI_MTE + m];
  int row0 = meta[MI_MTB + m];
  int n0 = blockIdx.x * 128;
  __shared__ __align__(16) char ldsA[8192];
  __shared__ __align__(16) char ldsB[8192];
  int wave = threadIdx.x >> 6, lane = threadIdx.x & 63;
  int wr = wave >> 1, wc = wave & 1;
  const __hip_bfloat16* Ab = Hb + (size_t)row0 * H_DIM;
  const __hip_bfloat16* Bb = w2t + ((size_t)e * D_DIM + n0) * H_DIM;

  f32x4 acc[4][4];
#pragma unroll
  for (int i = 0; i < 4; i++)
#pragma unroll
    for (int j = 0; j < 4; j++) acc[i][j] = 0.f;

  int rsel = lane & 15, kg = lane >> 4;
  for (int k0 = 0; k0 < H_DIM; k0 += 32) {
    stage_tile16(Ab + k0, H_DIM, ldsA, wave, lane);
    stage_tile16(Bb + k0, H_DIM, ldsB, wave, lane);
    asm volatile("s_waitcnt vmcnt(0)" ::: "memory");
    __syncthreads();
    short8 a[4], b[4];
#pragma unroll
    for (int f = 0; f < 4; f++) a[f] = frag_read(ldsA, wr * 64 + f * 16 + rsel, kg);
#pragma unroll
    for (int f = 0; f < 4; f++) b[f] = frag_read(ldsB, wc * 64 + f * 16 + rsel, kg);
#pragma unroll
    for (int fm = 0; fm < 4; fm++)
#pragma unroll
      for (int fn = 0; fn < 4; fn++)
        acc[fm][fn] = __builtin_amdgcn_mfma_f32_16x16x32_bf16(a[fm], b[fn], acc[fm][fn], 0, 0, 0);
    __syncthreads();
  }
  int rq = lane >> 4;
#pragma unroll
  for (int fm = 0; fm < 4; fm++)
#pragma unroll
    for (int fn = 0; fn < 4; fn++)
#pragma unroll
      for (int j = 0; j < 4; j++) {
        int r = wr * 64 + fm * 16 + rq * 4 + j;
        int c = wc * 64 + fn * 16 + rsel;
        Y[(size_t)(row0 + r) * D_DIM + (n0 + c)] = acc[fm][fn][j];
      }
}

// ---------------- combine: out[t] = w0*Y[p0] + w1*Y[p1] ----------------
__global__ __launch_bounds__(256) void combine_kernel(const int* __restrict__ slot_pos,
                                                      const float* __restrict__ slot_w,
                                                      const float* __restrict__ Y,
                                                      float* __restrict__ outp) {
  int tok = blockIdx.x;
  int p0 = slot_pos[tok * 2], p1 = slot_pos[tok * 2 + 1];
  float w0 = slot_w[tok * 2], w1 = slot_w[tok * 2 + 1];
  float4 y0 = ((const float4*)(Y + (size_t)p0 * D_DIM))[threadIdx.x];
  float4 y1 = ((const float4*)(Y + (size_t)p1 * D_DIM))[threadIdx.x];
  float4 r;
  r.x = w0 * y0.x + w1 * y1.x;
  r.y = w0 * y0.y + w1 * y1.y;
  r.z = w0 * y0.z + w1 * y1.z;
  r.w = w0 * y0.w + w1 * y1.w;
  ((float4*)(outp + (size_t)tok * D_DIM))[threadIdx.x] = r;
}

// ---------------- launch ----------------
extern "C" void kernel_launch(void* const* d_in, const int* in_sizes, int n_in,
                              void* d_out, int out_size, void* d_ws, size_t ws_size,
                              hipStream_t stream) {
  const float* x = (const float*)d_in[0];
  const float* Wr = (const float*)d_in[1];
  const float* w1 = (const float*)d_in[2];
  const float* w3 = (const float*)d_in[3];
  const float* w2 = (const float*)d_in[4];
  float* outp = (float*)d_out;

  char* ws = (char*)d_ws;
  size_t off = 0;
  auto alloc = [&](size_t bytes) -> char* {
    char* p = ws + off;
    off += (bytes + 255) & ~(size_t)255;
    return p;
  };
  __hip_bfloat16* w1t = (__hip_bfloat16*)alloc((size_t)E_EXP * H_DIM * D_DIM * 2);
  __hip_bfloat16* w3t = (__hip_bfloat16*)alloc((size_t)E_EXP * H_DIM * D_DIM * 2);
  __hip_bfloat16* w2t = (__hip_bfloat16*)alloc((size_t)E_EXP * D_DIM * H_DIM * 2);
  __hip_bfloat16* Xg = (__hip_bfloat16*)alloc((size_t)CAP_ROWS * D_DIM * 2);
  __hip_bfloat16* Hb = (__hip_bfloat16*)alloc((size_t)CAP_ROWS * H_DIM * 2);
  float* Y = (float*)alloc((size_t)CAP_ROWS * D_DIM * 4);
  float* slot_w = (float*)alloc(NSLOT * 4);
  int* slot_pos = (int*)alloc(NSLOT * 4);
  int* expert_sel = (int*)alloc(NSLOT * 4);
  float* Pbuf = (float*)alloc(2048 * 8 * 4);
  int* meta = (int*)alloc(2048);
  (void)ws_size; (void)in_sizes; (void)n_in; (void)out_size;

  init_kernel<<<dim3(1), dim3(64), 0, stream>>>(meta);
  transpose_convert<D_DIM, H_DIM><<<dim3(H_DIM / 32, D_DIM / 32, E_EXP), dim3(256), 0, stream>>>(w1, w1t);
  transpose_convert<D_DIM, H_DIM><<<dim3(H_DIM / 32, D_DIM / 32, E_EXP), dim3(256), 0, stream>>>(w3, w3t);
  transpose_convert<H_DIM, D_DIM><<<dim3(D_DIM / 32, H_DIM / 32, E_EXP), dim3(256), 0, stream>>>(w2, w2t);
  router_kernel<<<dim3(T_TOK / 4), dim3(256), 0, stream>>>(x, Wr, meta, Pbuf, expert_sel, slot_w);
  offsets_kernel<<<dim3(1), dim3(64), 0, stream>>>(meta, Pbuf, outp + (size_t)T_TOK * D_DIM);
  assign_gather_kernel<<<dim3(NSLOT), dim3(256), 0, stream>>>(expert_sel, meta, slot_pos, x, Xg);
  gemm1_kernel<<<dim3(H_DIM / 128, MT_MAX), dim3(256), 0, stream>>>(Xg, w1t, w3t, Hb, meta);
  gemm2_kernel<<<dim3(D_DIM / 128, MT_MAX), dim3(256), 0, stream>>>(Hb, w2t, Y, meta);
  combine_kernel<<<dim3(T_TOK), dim3(256), 0, stream>>>(slot_pos, slot_w, Y, outp);
}

// Round 2
// 713.582 us; speedup vs baseline: 1.3206x; 1.3206x over previous
//
#include <hip/hip_runtime.h>
#include <hip/hip_bf16.h>
#include <stdint.h>

// MoE top-2 (T=8192, D=1024, H=2816, E=8) — sparse grouped-GEMM implementation.
// R2: fast 64x64 transposes, ballot-aggregated assign, parallel offsets,
//     GEMMs BK=64 + XCD-chunked n-major swizzle.

#define T_TOK 8192
#define D_DIM 1024
#define H_DIM 2816
#define E_EXP 8
#define NSLOT 16384       // T * 2
#define CAP_ROWS 17408    // 136 * 128
#define MT_MAX 136

// meta int layout
#define MI_TOTAL 0
#define MI_CNT 8
#define MI_POS 16
#define MI_MTE 32
#define MI_MTB (32 + MT_MAX)

typedef __attribute__((ext_vector_type(8))) short short8;
typedef __attribute__((ext_vector_type(4))) float f32x4;

#define GLD16(gsrc, ldst) __builtin_amdgcn_global_load_lds( \
    (const __attribute__((address_space(1))) void*)(gsrc),  \
    (__attribute__((address_space(3))) void*)(ldst), 16, 0, 0)

// ---------------- init ----------------
__global__ __launch_bounds__(64) void init_kernel(int* meta) {
  if (threadIdx.x < E_EXP) meta[MI_CNT + threadIdx.x] = 0;
}

// ---------------- weight transpose + f32->bf16 ----------------
// in: (E, R, C) f32   out: (E, C, R) bf16.  64x64 tiles, coalesced both sides.
template <int R, int C>
__global__ __launch_bounds__(256) void transpose_convert(const float* __restrict__ in,
                                                         __hip_bfloat16* __restrict__ outp) {
  int e = blockIdx.z;
  int c0 = blockIdx.x * 64, r0 = blockIdx.y * 64;
  __shared__ float tile[64][65];
  int tid = threadIdx.x;
  int lc = (tid & 15) * 4;  // col 0..60 step 4
  int lr = tid >> 4;        // 0..15
  const float* src = in + ((size_t)e * R + r0) * C + c0;
#pragma unroll
  for (int i = 0; i < 4; i++) {
    float4 v = *(const float4*)(src + (size_t)(lr + i * 16) * C + lc);
    tile[lr + i * 16][lc + 0] = v.x;
    tile[lr + i * 16][lc + 1] = v.y;
    tile[lr + i * 16][lc + 2] = v.z;
    tile[lr + i * 16][lc + 3] = v.w;
  }
  __syncthreads();
  __hip_bfloat16* dst = outp + ((size_t)e * C + c0) * R + r0;
  int rB = (tid & 7) * 8;
#pragma unroll
  for (int i = 0; i < 2; i++) {
    int c = (tid >> 3) + i * 32;
    __align__(16) __hip_bfloat16 o[8];
#pragma unroll
    for (int k = 0; k < 8; k++) o[k] = __float2bfloat16(tile[rB + k][c]);
    *(short8*)(dst + (size_t)c * R + rB) = *(const short8*)o;
  }
}

// ---------------- router ----------------
__global__ __launch_bounds__(256) void router_kernel(const float* __restrict__ x,
                                                     const float* __restrict__ Wr,
                                                     int* __restrict__ meta,
                                                     float* __restrict__ Pbuf,
                                                     int* __restrict__ expert_sel,
                                                     float* __restrict__ slot_w) {
  int wave = threadIdx.x >> 6, lane = threadIdx.x & 63;
  int tok = blockIdx.x * 4 + wave;
  const float* xr = x + (size_t)tok * D_DIM;
  float acc[8];
#pragma unroll
  for (int e = 0; e < 8; e++) acc[e] = 0.f;
  for (int d = lane; d < D_DIM; d += 64) {
    float xv = xr[d];
    const float4* w4 = (const float4*)(Wr + d * 8);
    float4 wa = w4[0], wb = w4[1];
    acc[0] += xv * wa.x; acc[1] += xv * wa.y; acc[2] += xv * wa.z; acc[3] += xv * wa.w;
    acc[4] += xv * wb.x; acc[5] += xv * wb.y; acc[6] += xv * wb.z; acc[7] += xv * wb.w;
  }
#pragma unroll
  for (int e = 0; e < 8; e++) {
#pragma unroll
    for (int off = 32; off >= 1; off >>= 1) acc[e] += __shfl_xor(acc[e], off);
  }
  float mx = acc[0];
#pragma unroll
  for (int e = 1; e < 8; e++) mx = fmaxf(mx, acc[e]);
  float p[8], s = 0.f;
#pragma unroll
  for (int e = 0; e < 8; e++) { p[e] = expf(acc[e] - mx); s += p[e]; }
  float inv = 1.f / s;
#pragma unroll
  for (int e = 0; e < 8; e++) p[e] *= inv;
  int i0 = 0;
#pragma unroll
  for (int e = 1; e < 8; e++) if (p[e] > p[i0]) i0 = e;
  int i1 = (i0 == 0) ? 1 : 0;
#pragma unroll
  for (int e = 0; e < 8; e++) if (e != i0 && p[e] > p[i1]) i1 = e;
  float wsum = p[i0] + p[i1];

  __shared__ float sP[4][8];
  if (lane == 0) {
    expert_sel[tok * 2] = i0;
    expert_sel[tok * 2 + 1] = i1;
    slot_w[tok * 2] = p[i0] / wsum;
    slot_w[tok * 2 + 1] = p[i1] / wsum;
    atomicAdd(&meta[MI_CNT + i0], 1);
    atomicAdd(&meta[MI_CNT + i1], 1);
#pragma unroll
    for (int e = 0; e < 8; e++) sP[wave][e] = p[e];
  }
  __syncthreads();
  if (threadIdx.x < 8)
    Pbuf[threadIdx.x * 2048 + blockIdx.x] =
        sP[0][threadIdx.x] + sP[1][threadIdx.x] + sP[2][threadIdx.x] + sP[3][threadIdx.x];
}

// ---------------- offsets + aux loss (parallel reduce) ----------------
__global__ __launch_bounds__(256) void offsets_kernel(int* __restrict__ meta,
                                                      const float* __restrict__ Pbuf,
                                                      float* __restrict__ aux_out) {
  __shared__ float red[8][33];
  int t = threadIdx.x;
  int e = t >> 5, j = t & 31;
  float s = 0.f;
  for (int c = j; c < 2048; c += 32) s += Pbuf[e * 2048 + c];
  red[e][j] = s;
  __syncthreads();
  if (t == 0) {
    float psum[8];
    for (int ee = 0; ee < 8; ee++) {
      float ss = 0.f;
      for (int k = 0; k < 32; k++) ss += red[ee][k];
      psum[ee] = ss;
    }
    int off = 0, nt = 0;
    float aux = 0.f;
    for (int ee = 0; ee < 8; ee++) {
      int c = meta[MI_CNT + ee];
      meta[MI_POS + ee] = off;
      int tiles = (c + 127) >> 7;
      for (int jj = 0; jj < tiles; jj++) { meta[MI_MTE + nt] = ee; meta[MI_MTB + nt] = off + jj * 128; nt++; }
      off += tiles * 128;
      aux += ((float)c / 16384.f) * (psum[ee] / 8192.f);
    }
    meta[MI_TOTAL] = nt;
    *aux_out = 8.f * aux;
  }
}

// ---------------- assign: ballot-aggregated positions ----------------
__global__ __launch_bounds__(256) void assign_kernel(const int* __restrict__ expert_sel,
                                                     int* __restrict__ meta,
                                                     int* __restrict__ slot_pos) {
  int tid = threadIdx.x, wave = tid >> 6, lane = tid & 63;
  int slot = blockIdx.x * 256 + tid;
  int e = expert_sel[slot];
  __shared__ int cnt[4][8];
  __shared__ int base[8];
  __shared__ int woff[4][8];
  int rank = 0;
#pragma unroll
  for (int ee = 0; ee < 8; ee++) {
    unsigned long long msk = __ballot(e == ee);
    if (lane == 0) cnt[wave][ee] = __popcll(msk);
    if (e == ee) rank = __popcll(msk & ((1ull << lane) - 1ull));
  }
  __syncthreads();
  if (tid < 8) {
    int c0 = cnt[0][tid], c1 = cnt[1][tid], c2 = cnt[2][tid], c3 = cnt[3][tid];
    int tot = c0 + c1 + c2 + c3;
    base[tid] = atomicAdd(&meta[MI_POS + tid], tot);
    woff[0][tid] = 0; woff[1][tid] = c0; woff[2][tid] = c0 + c1; woff[3][tid] = c0 + c1 + c2;
  }
  __syncthreads();
  slot_pos[slot] = base[e] + woff[wave][e] + rank;
}

// ---------------- gather x rows as bf16 ----------------
__global__ __launch_bounds__(256) void gather_kernel(const int* __restrict__ slot_pos,
                                                     const float* __restrict__ x,
                                                     __hip_bfloat16* __restrict__ Xg) {
  int wave = threadIdx.x >> 6, lane = threadIdx.x & 63;
  int slot = blockIdx.x * 4 + wave;
  int pos = slot_pos[slot];
  int tok = slot >> 1;
  const float4* src = (const float4*)(x + (size_t)tok * D_DIM);
  __hip_bfloat16* dst = Xg + (size_t)pos * D_DIM;
#pragma unroll
  for (int p = 0; p < 4; p++) {
    float4 v = src[p * 64 + lane];
    union { ushort4 u4; __hip_bfloat16 h[4]; } cv;
    cv.h[0] = __float2bfloat16(v.x);
    cv.h[1] = __float2bfloat16(v.y);
    cv.h[2] = __float2bfloat16(v.z);
    cv.h[3] = __float2bfloat16(v.w);
    *(ushort4*)(dst + (p * 64 + lane) * 4) = cv.u4;
  }
}

// ---------------- GEMM helpers (BK=64) ----------------
// LDS tile: [128 rows][64 bf16] = 16KB. 16B granule g (0..7) XOR-swizzled with row&7.
__device__ __forceinline__ short8 frag_read64(const char* tile, int row, int gk) {
  int byte = (row << 7) | ((gk ^ (row & 7)) << 4);
  return *(const short8*)(tile + byte);
}

__device__ __forceinline__ void stage_tile64(const __hip_bfloat16* gbase, int ld, char* tile,
                                             int wave, int lane) {
#pragma unroll
  for (int i = 0; i < 4; i++) {
    int L = i * 4096 + wave * 1024 + lane * 16;
    int row = L >> 7;
    int g = (L >> 4) & 7;
    int gs = g ^ (row & 7);  // pre-swizzled global source, linear LDS dest
    const char* src = (const char*)(gbase + (size_t)row * ld) + gs * 16;
    GLD16(src, tile + i * 4096 + wave * 1024);
  }
}

// bijective XCD-chunked swizzle on flattened grid (nwg % 8 == 0), n-major tiling
__device__ __forceinline__ void tile_from_bid(int bid, int nwg, int* m, int* n) {
  int cpx = nwg >> 3;
  int u = (bid & 7) * cpx + (bid >> 3);
  *n = u / MT_MAX;
  *m = u % MT_MAX;
}

// ---------------- GEMM1: H = silu(Xg @ w1t^T) * (Xg @ w3t^T), bf16 out ----------------
__global__ __launch_bounds__(256, 2) void gemm1_kernel(const __hip_bfloat16* __restrict__ Xg,
                                                       const __hip_bfloat16* __restrict__ w1t,
                                                       const __hip_bfloat16* __restrict__ w3t,
                                                       __hip_bfloat16* __restrict__ Hb,
                                                       const int* __restrict__ meta) {
  int m, nIdx;
  tile_from_bid(blockIdx.x, (H_DIM / 128) * MT_MAX, &m, &nIdx);
  if (m >= meta[MI_TOTAL]) return;
  int e = meta[MI_MTE + m];
  int row0 = meta[MI_MTB + m];
  int n0 = nIdx * 128;
  __shared__ __align__(16) char ldsA[16384];
  __shared__ __align__(16) char ldsB1[16384];
  __shared__ __align__(16) char ldsB3[16384];
  int wave = threadIdx.x >> 6, lane = threadIdx.x & 63;
  int wr = wave >> 1, wc = wave & 1;
  const __hip_bfloat16* Ab = Xg + (size_t)row0 * D_DIM;
  const __hip_bfloat16* B1b = w1t + ((size_t)e * H_DIM + n0) * D_DIM;
  const __hip_bfloat16* B3b = w3t + ((size_t)e * H_DIM + n0) * D_DIM;

  f32x4 acc1[4][4], acc3[4][4];
#pragma unroll
  for (int i = 0; i < 4; i++)
#pragma unroll
    for (int j = 0; j < 4; j++) { acc1[i][j] = 0.f; acc3[i][j] = 0.f; }

  int rsel = lane & 15, kg = lane >> 4;
  for (int k0 = 0; k0 < D_DIM; k0 += 64) {
    stage_tile64(Ab + k0, D_DIM, ldsA, wave, lane);
    stage_tile64(B1b + k0, D_DIM, ldsB1, wave, lane);
    stage_tile64(B3b + k0, D_DIM, ldsB3, wave, lane);
    asm volatile("s_waitcnt vmcnt(0)" ::: "memory");
    __syncthreads();
#pragma unroll
    for (int kk = 0; kk < 2; kk++) {
      int gk = kk * 4 + kg;
      short8 a[4], b1[4], b3[4];
#pragma unroll
      for (int f = 0; f < 4; f++) a[f] = frag_read64(ldsA, wr * 64 + f * 16 + rsel, gk);
#pragma unroll
      for (int f = 0; f < 4; f++) b1[f] = frag_read64(ldsB1, wc * 64 + f * 16 + rsel, gk);
#pragma unroll
      for (int f = 0; f < 4; f++) b3[f] = frag_read64(ldsB3, wc * 64 + f * 16 + rsel, gk);
#pragma unroll
      for (int fm = 0; fm < 4; fm++)
#pragma unroll
        for (int fn = 0; fn < 4; fn++) {
          acc1[fm][fn] = __builtin_amdgcn_mfma_f32_16x16x32_bf16(a[fm], b1[fn], acc1[fm][fn], 0, 0, 0);
          acc3[fm][fn] = __builtin_amdgcn_mfma_f32_16x16x32_bf16(a[fm], b3[fn], acc3[fm][fn], 0, 0, 0);
        }
    }
    __syncthreads();
  }
  int rq = lane >> 4;
#pragma unroll
  for (int fm = 0; fm < 4; fm++)
#pragma unroll
    for (int fn = 0; fn < 4; fn++)
#pragma unroll
      for (int j = 0; j < 4; j++) {
        int r = wr * 64 + fm * 16 + rq * 4 + j;
        int c = wc * 64 + fn * 16 + rsel;
        float v1 = acc1[fm][fn][j], v3 = acc3[fm][fn][j];
        float h = (v1 / (1.f + expf(-v1))) * v3;  // silu(v1)*v3
        Hb[(size_t)(row0 + r) * H_DIM + (n0 + c)] = __float2bfloat16(h);
      }
}

// ---------------- GEMM2: Y = Hb @ w2t^T (fp32 out) ----------------
__global__ __launch_bounds__(256, 2) void gemm2_kernel(const __hip_bfloat16* __restrict__ Hb,
                                                       const __hip_bfloat16* __restrict__ w2t,
                                                       float* __restrict__ Y,
                                                       const int* __restrict__ meta) {
  int m, nIdx;
  tile_from_bid(blockIdx.x, (D_DIM / 128) * MT_MAX, &m, &nIdx);
  if (m >= meta[MI_TOTAL]) return;
  int e = meta[MI_MTE + m];
  int row0 = meta[MI_MTB + m];
  int n0 = nIdx * 128;
  __shared__ __align__(16) char ldsA[16384];
  __shared__ __align__(16) char ldsB[16384];
  int wave = threadIdx.x >> 6, lane = threadIdx.x & 63;
  int wr = wave >> 1, wc = wave & 1;
  const __hip_bfloat16* Ab = Hb + (size_t)row0 * H_DIM;
  const __hip_bfloat16* Bb = w2t + ((size_t)e * D_DIM + n0) * H_DIM;

  f32x4 acc[4][4];
#pragma unroll
  for (int i = 0; i < 4; i++)
#pragma unroll
    for (int j = 0; j < 4; j++) acc[i][j] = 0.f;

  int rsel = lane & 15, kg = lane >> 4;
  for (int k0 = 0; k0 < H_DIM; k0 += 64) {
    stage_tile64(Ab + k0, H_DIM, ldsA, wave, lane);
    stage_tile64(Bb + k0, H_DIM, ldsB, wave, lane);
    asm volatile("s_waitcnt vmcnt(0)" ::: "memory");
    __syncthreads();
#pragma unroll
    for (int kk = 0; kk < 2; kk++) {
      int gk = kk * 4 + kg;
      short8 a[4], b[4];
#pragma unroll
      for (int f = 0; f < 4; f++) a[f] = frag_read64(ldsA, wr * 64 + f * 16 + rsel, gk);
#pragma unroll
      for (int f = 0; f < 4; f++) b[f] = frag_read64(ldsB, wc * 64 + f * 16 + rsel, gk);
#pragma unroll
      for (int fm = 0; fm < 4; fm++)
#pragma unroll
        for (int fn = 0; fn < 4; fn++)
          acc[fm][fn] = __builtin_amdgcn_mfma_f32_16x16x32_bf16(a[fm], b[fn], acc[fm][fn], 0, 0, 0);
    }
    __syncthreads();
  }
  int rq = lane >> 4;
#pragma unroll
  for (int fm = 0; fm < 4; fm++)
#pragma unroll
    for (int fn = 0; fn < 4; fn++)
#pragma unroll
      for (int j = 0; j < 4; j++) {
        int r = wr * 64 + fm * 16 + rq * 4 + j;
        int c = wc * 64 + fn * 16 + rsel;
        Y[(size_t)(row0 + r) * D_DIM + (n0 + c)] = acc[fm][fn][j];
      }
}

// ---------------- combine: out[t] = w0*Y[p0] + w1*Y[p1] ----------------
__global__ __launch_bounds__(256) void combine_kernel(const int* __restrict__ slot_pos,
                                                      const float* __restrict__ slot_w,
                                                      const float* __restrict__ Y,
                                                      float* __restrict__ outp) {
  int tok = blockIdx.x;
  int p0 = slot_pos[tok * 2], p1 = slot_pos[tok * 2 + 1];
  float w0 = slot_w[tok * 2], w1 = slot_w[tok * 2 + 1];
  float4 y0 = ((const float4*)(Y + (size_t)p0 * D_DIM))[threadIdx.x];
  float4 y1 = ((const float4*)(Y + (size_t)p1 * D_DIM))[threadIdx.x];
  float4 r;
  r.x = w0 * y0.x + w1 * y1.x;
  r.y = w0 * y0.y + w1 * y1.y;
  r.z = w0 * y0.z + w1 * y1.z;
  r.w = w0 * y0.w + w1 * y1.w;
  ((float4*)(outp + (size_t)tok * D_DIM))[threadIdx.x] = r;
}

// ---------------- launch ----------------
extern "C" void kernel_launch(void* const* d_in, const int* in_sizes, int n_in,
                              void* d_out, int out_size, void* d_ws, size_t ws_size,
                              hipStream_t stream) {
  const float* x = (const float*)d_in[0];
  const float* Wr = (const float*)d_in[1];
  const float* w1 = (const float*)d_in[2];
  const float* w3 = (const float*)d_in[3];
  const float* w2 = (const float*)d_in[4];
  float* outp = (float*)d_out;

  char* ws = (char*)d_ws;
  size_t off = 0;
  auto alloc = [&](size_t bytes) -> char* {
    char* p = ws + off;
    off += (bytes + 255) & ~(size_t)255;
    return p;
  };
  __hip_bfloat16* w1t = (__hip_bfloat16*)alloc((size_t)E_EXP * H_DIM * D_DIM * 2);
  __hip_bfloat16* w3t = (__hip_bfloat16*)alloc((size_t)E_EXP * H_DIM * D_DIM * 2);
  __hip_bfloat16* w2t = (__hip_bfloat16*)alloc((size_t)E_EXP * D_DIM * H_DIM * 2);
  __hip_bfloat16* Xg = (__hip_bfloat16*)alloc((size_t)CAP_ROWS * D_DIM * 2);
  __hip_bfloat16* Hb = (__hip_bfloat16*)alloc((size_t)CAP_ROWS * H_DIM * 2);
  float* Y = (float*)alloc((size_t)CAP_ROWS * D_DIM * 4);
  float* slot_w = (float*)alloc(NSLOT * 4);
  int* slot_pos = (int*)alloc(NSLOT * 4);
  int* expert_sel = (int*)alloc(NSLOT * 4);
  float* Pbuf = (float*)alloc(2048 * 8 * 4);
  int* meta = (int*)alloc(2048);
  (void)ws_size; (void)in_sizes; (void)n_in; (void)out_size;

  init_kernel<<<dim3(1), dim3(64), 0, stream>>>(meta);
  transpose_convert<D_DIM, H_DIM><<<dim3(H_DIM / 64, D_DIM / 64, E_EXP), dim3(256), 0, stream>>>(w1, w1t);
  transpose_convert<D_DIM, H_DIM><<<dim3(H_DIM / 64, D_DIM / 64, E_EXP), dim3(256), 0, stream>>>(w3, w3t);
  transpose_convert<H_DIM, D_DIM><<<dim3(D_DIM / 64, H_DIM / 64, E_EXP), dim3(256), 0, stream>>>(w2, w2t);
  router_kernel<<<dim3(T_TOK / 4), dim3(256), 0, stream>>>(x, Wr, meta, Pbuf, expert_sel, slot_w);
  offsets_kernel<<<dim3(1), dim3(256), 0, stream>>>(meta, Pbuf, outp + (size_t)T_TOK * D_DIM);
  assign_kernel<<<dim3(NSLOT / 256), dim3(256), 0, stream>>>(expert_sel, meta, slot_pos);
  gather_kernel<<<dim3(NSLOT / 4), dim3(256), 0, stream>>>(slot_pos, x, Xg);
  gemm1_kernel<<<dim3((H_DIM / 128) * MT_MAX), dim3(256), 0, stream>>>(Xg, w1t, w3t, Hb, meta);
  gemm2_kernel<<<dim3((D_DIM / 128) * MT_MAX), dim3(256), 0, stream>>>(Hb, w2t, Y, meta);
  combine_kernel<<<dim3(T_TOK), dim3(256), 0, stream>>>(slot_pos, slot_w, Y, outp);
}